// Round 5
// baseline (3140.922 us; speedup 1.0000x reference)
//
#include <hip/hip_runtime.h>
#include <hip/hip_cooperative_groups.h>
#include <math.h>

namespace cg = cooperative_groups;

#define NN 512
#define EMBD 10
#define HH 64
#define DINV 2
#define CIN 66
#define TT 12
#define BB 16
#define LH 130
#define LG 520
#define PART ((size_t)BB * NN * CIN)

typedef __attribute__((ext_vector_type(8))) short short8;
typedef __attribute__((ext_vector_type(4))) float f32x4;

__device__ __forceinline__ float sigmoidf_(float x) { return 1.f / (1.f + __expf(-x)); }
__device__ __forceinline__ float tanhf_(float x)    { return 1.f - 2.f / (1.f + __expf(2.f * x)); }
__device__ __forceinline__ float bl_(unsigned p) { return __uint_as_float(p << 16); }
__device__ __forceinline__ float bh_(unsigned p) { return __uint_as_float(p & 0xffff0000u); }
__device__ __forceinline__ unsigned bf16rne_(float f) {
    unsigned u = __float_as_uint(f);
    u += 0x7fff + ((u >> 16) & 1);
    return u >> 16;
}
__device__ __forceinline__ void split_(float v, unsigned& hi, unsigned& lo) {
    hi = bf16rne_(v);
    float hif = __uint_as_float(hi << 16);
    lo = bf16rne_(v - hif);
}

// ---------------- S_base = softmax(relu(emb @ emb^T)) ----------------
__global__ __launch_bounds__(256) void sbase_kernel(const float* __restrict__ emb,
                                                    float* __restrict__ Sb) {
    const int n = blockIdx.x;
    const int tid = threadIdx.x;
    __shared__ float en[EMBD];
    __shared__ float redw[4];
    if (tid < EMBD) en[tid] = emb[n * EMBD + tid];
    __syncthreads();
    float v[2];
    #pragma unroll
    for (int q = 0; q < 2; q++) {
        int m = tid + q * 256;
        float s = 0.f;
        #pragma unroll
        for (int d = 0; d < EMBD; d++) s += en[d] * emb[m * EMBD + d];
        v[q] = fmaxf(s, 0.f);
    }
    float mx = fmaxf(v[0], v[1]);
    for (int off = 32; off >= 1; off >>= 1) mx = fmaxf(mx, __shfl_xor(mx, off));
    if ((tid & 63) == 0) redw[tid >> 6] = mx;
    __syncthreads();
    mx = fmaxf(fmaxf(redw[0], redw[1]), fmaxf(redw[2], redw[3]));
    __syncthreads();
    v[0] = __expf(v[0] - mx);
    v[1] = __expf(v[1] - mx);
    float sm = v[0] + v[1];
    for (int off = 32; off >= 1; off >>= 1) sm += __shfl_xor(sm, off);
    if ((tid & 63) == 0) redw[tid >> 6] = sm;
    __syncthreads();
    sm = redw[0] + redw[1] + redw[2] + redw[3];
    float inv = 1.f / sm;
    Sb[n * NN + tid]       = v[0] * inv;
    Sb[n * NN + tid + 256] = v[1] * inv;
}

// ------------- per-node biases (f32) -------------
__global__ __launch_bounds__(256) void combine_kernel(const float* __restrict__ emb,
                                                      const float* __restrict__ pool,
                                                      float* __restrict__ out,
                                                      int per_n, int total) {
    for (int idx = blockIdx.x * 256 + threadIdx.x; idx < total; idx += gridDim.x * 256) {
        int n = idx / per_n;
        int rem = idx - n * per_n;
        float a = 0.f;
        #pragma unroll
        for (int d = 0; d < EMBD; d++) a += emb[n * EMBD + d] * pool[d * per_n + rem];
        out[idx] = a;
    }
}

// ------------- per-node weights -> fragment-ordered bf16 hi/lo -------------
__global__ __launch_bounds__(256) void combine_frag_kernel(const float* __restrict__ emb,
                                                           const float* __restrict__ pool,
                                                           unsigned short* __restrict__ outU,
                                                           int O, int OT) {
    size_t total = (size_t)NN * OT * 5 * 512;
    for (size_t idx = (size_t)blockIdx.x * 256 + threadIdx.x; idx < total;
         idx += (size_t)gridDim.x * 256) {
        int j = idx & 7;
        int l = (idx >> 3) & 63;
        size_t r = idx >> 9;
        int kc = (int)(r % 5); r /= 5;
        int ot = (int)(r % OT);
        int n  = (int)(r / OT);
        int kp = kc * 32 + ((l >> 4) << 3) + j;
        int o = ot * 16 + (l & 15);
        float v = 0.f;
        if (kp < 2 * CIN) {
            int kk = (kp >= CIN) ? 1 : 0;
            int i = kp - CIN * kk;
            const float* p = pool + ((size_t)(kk * CIN + i)) * O + o;
            #pragma unroll
            for (int d = 0; d < EMBD; d++)
                v += emb[n * EMBD + d] * p[(size_t)d * (2 * CIN) * O];
        }
        unsigned hi, lo;
        split_(v, hi, lo);
        size_t base = (((size_t)n * OT + ot) * 5 + kc) * 1024;
        outU[base + l * 8 + j] = (unsigned short)hi;
        outU[base + 512 + l * 8 + j] = (unsigned short)lo;
    }
}

// ------------- pack LSTM weights -------------
__global__ __launch_bounds__(256) void pack_kernel(const float* __restrict__ w,
                                                   unsigned* __restrict__ wp, int K) {
    int idx = blockIdx.x * 256 + threadIdx.x;
    int KH = K >> 1;
    if (idx < KH * LG) {
        int kk = idx / LG, j = idx - kk * LG;
        wp[idx] = bf16rne_(w[j * K + 2 * kk]) | (bf16rne_(w[j * K + 2 * kk + 1]) << 16);
    }
}

// ================= persistent cooperative GRU =================
struct SpmmS {
    unsigned A_h[2048], A_l[2048];
    unsigned B_h[2560], B_l[2560];
};
struct GateS {
    unsigned short A_h[16 * 168], A_l[16 * 168];
};
union CoopS { SpmmS sp; GateS gt; };

__device__ __forceinline__ void spmm_phase(const float* __restrict__ Sb,
                                           const float* __restrict__ mask,
                                           const float* __restrict__ ent,
                                           const float* __restrict__ state,
                                           const float* __restrict__ cand,
                                           float* __restrict__ out,
                                           int t, int mode, SpmmS& sm,
                                           int blk, int tid) {
    const int lane = tid & 63;
    const int w = tid >> 6;
    const int n0 = (blk & 7) * 64;
    const int b = (blk >> 3) & 15;
    const int half = blk >> 7;
    float* __restrict__ outp = out + (size_t)half * PART;
    const float* mrow = mask + (size_t)(b * TT + t) * NN * NN;

    f32x4 acc[5];
    #pragma unroll
    for (int ct = 0; ct < 5; ct++) acc[ct] = (f32x4){0.f, 0.f, 0.f, 0.f};

    for (int r = 0; r < 4; r++) {
        const int m0 = half * 256 + r * 64;
        for (int p = tid; p < 2048; p += 256) {
            int jp = p & 3, l = (p >> 2) & 63, kc = (p >> 8) & 1, ww = p >> 9;
            int n_local = (ww << 4) | (l & 15);
            int m_local = (kc << 5) | (((l >> 4) & 3) << 3) | (jp << 1);
            size_t g = (size_t)(n0 + n_local) * NN + (m0 + m_local);
            float2 sb = *(const float2*)(Sb + g);
            float2 mk = *(const float2*)(mrow + g);
            unsigned h0, l0, h1, l1;
            split_(sb.x * mk.x, h0, l0);
            split_(sb.y * mk.y, h1, l1);
            int widx = ((ww * 2 + kc) << 8) + l * 4 + jp;
            sm.A_h[widx] = h0 | (h1 << 16);
            sm.A_l[widx] = l0 | (l1 << 16);
        }
        for (int p = tid; p < 2560; p += 256) {
            int jp = p & 3, l = (p >> 2) & 63, kc = (p >> 8) & 1, ct = p >> 9;
            int c = (ct << 4) | (l & 15);
            int m_local = (kc << 5) | (((l >> 4) & 3) << 3) | (jp << 1);
            int m = m0 + m_local;
            float x0 = 0.f, x1 = 0.f;
            if (c < CIN) {
                if (mode == 0) {
                    if (c < DINV) {
                        x0 = ent[((size_t)(b * TT + t) * NN + m) * DINV + c];
                        x1 = ent[((size_t)(b * TT + t) * NN + m + 1) * DINV + c];
                    } else {
                        x0 = state[((size_t)b * NN + m) * HH + (c - DINV)];
                        x1 = state[((size_t)b * NN + m + 1) * HH + (c - DINV)];
                    }
                } else {
                    x0 = cand[(size_t)b * NN * CIN + m * CIN + c];
                    x1 = cand[(size_t)b * NN * CIN + (m + 1) * CIN + c];
                }
            }
            unsigned h0, l0, h1, l1;
            split_(x0, h0, l0);
            split_(x1, h1, l1);
            int widx = ((ct * 2 + kc) << 8) + l * 4 + jp;
            sm.B_h[widx] = h0 | (h1 << 16);
            sm.B_l[widx] = l0 | (l1 << 16);
        }
        __syncthreads();
        #pragma unroll
        for (int kc = 0; kc < 2; kc++) {
            short8 ah = ((const short8*)sm.A_h)[(w * 2 + kc) * 64 + lane];
            short8 al = ((const short8*)sm.A_l)[(w * 2 + kc) * 64 + lane];
            #pragma unroll
            for (int ct = 0; ct < 5; ct++) {
                short8 bh = ((const short8*)sm.B_h)[(ct * 2 + kc) * 64 + lane];
                short8 bl = ((const short8*)sm.B_l)[(ct * 2 + kc) * 64 + lane];
                acc[ct] = __builtin_amdgcn_mfma_f32_16x16x32_bf16(ah, bh, acc[ct], 0, 0, 0);
                acc[ct] = __builtin_amdgcn_mfma_f32_16x16x32_bf16(ah, bl, acc[ct], 0, 0, 0);
                acc[ct] = __builtin_amdgcn_mfma_f32_16x16x32_bf16(al, bh, acc[ct], 0, 0, 0);
            }
        }
        __syncthreads();
    }
    const int col = lane & 15, rq = lane >> 4;
    #pragma unroll
    for (int ct = 0; ct < 5; ct++) {
        int c = ct * 16 + col;
        if (c < CIN) {
            #pragma unroll
            for (int reg = 0; reg < 4; reg++) {
                int n = n0 + w * 16 + rq * 4 + reg;
                outp[(size_t)b * NN * CIN + n * CIN + c] = acc[ct][reg];
            }
        }
    }
}

__device__ __forceinline__ void gate_phase(const float* __restrict__ ent,
                                           const float* __restrict__ state,
                                           const float* __restrict__ xg1,
                                           const unsigned short* __restrict__ WgF,
                                           const float* __restrict__ bg,
                                           float* __restrict__ cand,
                                           float* __restrict__ rbuf,
                                           int t, GateS& sm, int blk, int tid) {
    const int lane = tid & 63;
    const int w = tid >> 6;
    for (int nn = 0; nn < 2; nn++) {
        const int n = blk * 2 + nn;
        __syncthreads();
        for (int idx = tid; idx < 16 * 36; idx += 256) {
            int b = idx / 36, k = 132 + idx - b * 36;
            sm.A_h[b * 168 + k] = 0; sm.A_l[b * 168 + k] = 0;
        }
        for (int idx = tid; idx < 16 * 132; idx += 256) {
            int b = idx / 132, ip = idx - b * 132;
            float v;
            if (ip < CIN) {
                v = (ip < DINV) ? ent[((size_t)(b * TT + t) * NN + n) * DINV + ip]
                                : state[((size_t)b * NN + n) * HH + (ip - DINV)];
            } else {
                size_t g = (size_t)b * NN * CIN + n * CIN + (ip - CIN);
                v = xg1[g] + xg1[g + PART];
            }
            unsigned hi, lo;
            split_(v, hi, lo);
            sm.A_h[b * 168 + ip] = (unsigned short)hi;
            sm.A_l[b * 168 + ip] = (unsigned short)lo;
        }
        __syncthreads();

        f32x4 acc0 = {0.f, 0.f, 0.f, 0.f}, acc1 = {0.f, 0.f, 0.f, 0.f};
        const unsigned short* Wn = WgF + (size_t)n * (8 * 5 * 1024);
        #pragma unroll
        for (int kc = 0; kc < 5; kc++) {
            int aoff = (lane & 15) * 168 + kc * 32 + (lane >> 4) * 8;
            short8 ah = *(const short8*)&sm.A_h[aoff];
            short8 al = *(const short8*)&sm.A_l[aoff];
            const unsigned short* f0 = Wn + ((size_t)(w * 5) + kc) * 1024 + lane * 8;
            short8 bh = *(const short8*)f0;
            short8 bl = *(const short8*)(f0 + 512);
            acc0 = __builtin_amdgcn_mfma_f32_16x16x32_bf16(ah, bh, acc0, 0, 0, 0);
            acc0 = __builtin_amdgcn_mfma_f32_16x16x32_bf16(ah, bl, acc0, 0, 0, 0);
            acc0 = __builtin_amdgcn_mfma_f32_16x16x32_bf16(al, bh, acc0, 0, 0, 0);
            const unsigned short* f1 = Wn + ((size_t)((w + 4) * 5) + kc) * 1024 + lane * 8;
            short8 bh1 = *(const short8*)f1;
            short8 bl1 = *(const short8*)(f1 + 512);
            acc1 = __builtin_amdgcn_mfma_f32_16x16x32_bf16(ah, bh1, acc1, 0, 0, 0);
            acc1 = __builtin_amdgcn_mfma_f32_16x16x32_bf16(ah, bl1, acc1, 0, 0, 0);
            acc1 = __builtin_amdgcn_mfma_f32_16x16x32_bf16(al, bh1, acc1, 0, 0, 0);
        }
        const int col = lane & 15, rq = lane >> 4;
        #pragma unroll
        for (int e = 0; e < 2; e++) {
            int o = (w + e * 4) * 16 + col;
            f32x4 a = e ? acc1 : acc0;
            float bias = bg[n * 128 + o];
            #pragma unroll
            for (int reg = 0; reg < 4; reg++) {
                int b = rq * 4 + reg;
                float zr = sigmoidf_(a[reg] + bias);
                if (o < HH)
                    cand[(size_t)b * NN * CIN + n * CIN + DINV + o] =
                        zr * state[((size_t)b * NN + n) * HH + o];
                else
                    rbuf[((size_t)b * NN + n) * HH + (o - HH)] = zr;
            }
        }
        if (tid < 32) {
            int b = tid >> 1, i = tid & 1;
            cand[(size_t)b * NN * CIN + n * CIN + i] =
                ent[((size_t)(b * TT + t) * NN + n) * DINV + i];
        }
    }
}

__device__ __forceinline__ void update_phase(const float* __restrict__ cand,
                                             const float* __restrict__ xg2,
                                             const unsigned short* __restrict__ WuF,
                                             const float* __restrict__ bu,
                                             const float* __restrict__ rbuf,
                                             float* __restrict__ state,
                                             GateS& sm, int blk, int tid) {
    const int lane = tid & 63;
    const int w = tid >> 6;
    for (int nn = 0; nn < 2; nn++) {
        const int n = blk * 2 + nn;
        __syncthreads();
        for (int idx = tid; idx < 16 * 36; idx += 256) {
            int b = idx / 36, k = 132 + idx - b * 36;
            sm.A_h[b * 168 + k] = 0; sm.A_l[b * 168 + k] = 0;
        }
        for (int idx = tid; idx < 16 * 132; idx += 256) {
            int b = idx / 132, ip = idx - b * 132;
            float v;
            if (ip < CIN) {
                v = cand[(size_t)b * NN * CIN + n * CIN + ip];
            } else {
                size_t g = (size_t)b * NN * CIN + n * CIN + (ip - CIN);
                v = xg2[g] + xg2[g + PART];
            }
            unsigned hi, lo;
            split_(v, hi, lo);
            sm.A_h[b * 168 + ip] = (unsigned short)hi;
            sm.A_l[b * 168 + ip] = (unsigned short)lo;
        }
        __syncthreads();

        f32x4 acc = {0.f, 0.f, 0.f, 0.f};
        const unsigned short* Wn = WuF + (size_t)n * (4 * 5 * 1024);
        #pragma unroll
        for (int kc = 0; kc < 5; kc++) {
            int aoff = (lane & 15) * 168 + kc * 32 + (lane >> 4) * 8;
            short8 ah = *(const short8*)&sm.A_h[aoff];
            short8 al = *(const short8*)&sm.A_l[aoff];
            const unsigned short* f0 = Wn + ((size_t)(w * 5) + kc) * 1024 + lane * 8;
            short8 bh = *(const short8*)f0;
            short8 bl = *(const short8*)(f0 + 512);
            acc = __builtin_amdgcn_mfma_f32_16x16x32_bf16(ah, bh, acc, 0, 0, 0);
            acc = __builtin_amdgcn_mfma_f32_16x16x32_bf16(ah, bl, acc, 0, 0, 0);
            acc = __builtin_amdgcn_mfma_f32_16x16x32_bf16(al, bh, acc, 0, 0, 0);
        }
        const int col = lane & 15, rq = lane >> 4;
        int o = w * 16 + col;
        float bias = bu[n * HH + o];
        #pragma unroll
        for (int reg = 0; reg < 4; reg++) {
            int b = rq * 4 + reg;
            float hc = tanhf_(acc[reg] + bias);
            size_t g = ((size_t)b * NN + n) * HH + o;
            float rr = rbuf[g];
            state[g] = rr * state[g] + (1.f - rr) * hc;
        }
    }
}

__global__ __launch_bounds__(256) void gru_coop_kernel(
    const float* __restrict__ Sb, const float* __restrict__ mask,
    const float* __restrict__ ent, float* __restrict__ state,
    float* __restrict__ cand, float* __restrict__ xgP,
    const unsigned short* __restrict__ WgF, const float* __restrict__ bgc,
    const unsigned short* __restrict__ WuF, const float* __restrict__ buc,
    float* __restrict__ rbuf) {
    cg::grid_group grid = cg::this_grid();
    __shared__ CoopS sm;
    const int blk = blockIdx.x;
    const int tid = threadIdx.x;

    for (int i = blk * 256 + tid; i < BB * NN * HH; i += 256 * 256) state[i] = 0.f;
    grid.sync();

    for (int t = 0; t < TT; t++) {
        spmm_phase(Sb, mask, ent, state, nullptr, xgP, t, 0, sm.sp, blk, tid);
        grid.sync();
        gate_phase(ent, state, xgP, WgF, bgc, cand, rbuf, t, sm.gt, blk, tid);
        grid.sync();
        spmm_phase(Sb, mask, ent, state, cand, xgP, t, 1, sm.sp, blk, tid);
        grid.sync();
        update_phase(cand, xgP, WuF, buc, rbuf, state, sm.gt, blk, tid);
        grid.sync();
    }
}

// ------------- fused 2-layer LSTM (unchanged) -------------
__global__ __launch_bounds__(512) void lstm_fused_kernel(
    const float* __restrict__ sr,
    const unsigned* __restrict__ wp_ih0, const float* __restrict__ Wih0,
    const float* __restrict__ bih0, const float* __restrict__ bhh0,
    const unsigned* __restrict__ wp_hh0, const float* __restrict__ Whh0,
    const unsigned* __restrict__ wp_ih1, const float* __restrict__ Wih1,
    const float* __restrict__ bih1, const float* __restrict__ bhh1,
    const unsigned* __restrict__ wp_hh1, const float* __restrict__ Whh1,
    float* __restrict__ h2last) {
    const int b = blockIdx.x;
    const int tid = threadIdx.x;
    const int lane = tid & 63;
    const int wv = tid >> 6;
    __shared__ __align__(16) float xp[32 * 520];
    __shared__ __align__(16) float h1s[32 * 132];
    __shared__ __align__(16) float xs[32 * 64];
    __shared__ __align__(16) float hS[132], cS[132];
    __shared__ float gS[520];
    __shared__ float WeX[130 * 8];
    unsigned wpk[65];

    for (int l = tid; l < 32 * 64; l += 512) xs[l] = sr[(size_t)b * 2048 + l];
    #pragma unroll
    for (int kk = 0; kk < 32; kk++) wpk[kk] = wp_ih0[kk * 520 + tid];
    for (int l = tid; l < 64 * 8; l += 512) { int k = l >> 3, je = l & 7; WeX[l] = Wih0[(512 + je) * 64 + k]; }
    __syncthreads();
    {
        float bias = bih0[tid] + bhh0[tid];
        for (int t = 0; t < 32; t++) {
            const float4* x4 = (const float4*)&xs[t * 64];
            float acc = bias;
            #pragma unroll
            for (int q = 0; q < 16; q++) {
                float4 xv = x4[q];
                unsigned pa = wpk[2 * q], pb = wpk[2 * q + 1];
                acc += xv.x * bl_(pa) + xv.y * bh_(pa) + xv.z * bl_(pb) + xv.w * bh_(pb);
            }
            xp[t * 520 + tid] = acc;
        }
        if (tid < 256) {
            int je = tid & 7, t = tid >> 3;
            float a = bih0[512 + je] + bhh0[512 + je];
            for (int k = 0; k < 64; k++) a += xs[t * 64 + k] * WeX[k * 8 + je];
            xp[t * 520 + 512 + je] = a;
        }
    }
    __syncthreads();

    #pragma unroll
    for (int kk = 0; kk < 65; kk++) wpk[kk] = wp_hh0[kk * 520 + tid];
    for (int l = tid; l < 130 * 8; l += 512) { int k = l >> 3, je = l & 7; WeX[l] = Whh0[(512 + je) * 130 + k]; }
    for (int l = tid; l < 132; l += 512) { hS[l] = 0.f; cS[l] = 0.f; }
    __syncthreads();
    {
        float we0 = WeX[lane * 8 + wv];
        float we1 = WeX[(lane + 64) * 8 + wv];
        float we2 = (lane < 2) ? WeX[(lane + 128) * 8 + wv] : 0.f;
        for (int t = 0; t < 32; t++) {
            float acc = xp[t * 520 + tid];
            const float4* h4 = (const float4*)hS;
            #pragma unroll
            for (int q = 0; q < 32; q++) {
                float4 hv = h4[q];
                unsigned pa = wpk[2 * q], pb = wpk[2 * q + 1];
                acc += hv.x * bl_(pa) + hv.y * bh_(pa) + hv.z * bl_(pb) + hv.w * bh_(pb);
            }
            { unsigned pc = wpk[64]; acc += hS[128] * bl_(pc) + hS[129] * bh_(pc); }
            gS[tid] = acc;
            float p = hS[lane] * we0 + hS[lane + 64] * we1;
            if (lane < 2) p += hS[lane + 128] * we2;
            #pragma unroll
            for (int off = 32; off >= 1; off >>= 1) p += __shfl_xor(p, off);
            if (lane == 0) gS[512 + wv] = xp[t * 520 + 512 + wv] + p;
            __syncthreads();
            if (tid < 130) {
                float iv = sigmoidf_(gS[tid]);
                float fv = sigmoidf_(gS[130 + tid]);
                float gv = tanhf_(gS[260 + tid]);
                float ov = sigmoidf_(gS[390 + tid]);
                float cv = fv * cS[tid] + iv * gv;
                cS[tid] = cv;
                float hv = ov * tanhf_(cv);
                hS[tid] = hv;
                h1s[t * 132 + tid] = hv;
            }
            __syncthreads();
        }
    }

    #pragma unroll
    for (int kk = 0; kk < 65; kk++) wpk[kk] = wp_ih1[kk * 520 + tid];
    for (int l = tid; l < 130 * 8; l += 512) { int k = l >> 3, je = l & 7; WeX[l] = Wih1[(512 + je) * 130 + k]; }
    __syncthreads();
    {
        float bias = bih1[tid] + bhh1[tid];
        for (int t = 0; t < 32; t++) {
            const float4* x4 = (const float4*)&h1s[t * 132];
            float acc = bias;
            #pragma unroll
            for (int q = 0; q < 32; q++) {
                float4 xv = x4[q];
                unsigned pa = wpk[2 * q], pb = wpk[2 * q + 1];
                acc += xv.x * bl_(pa) + xv.y * bh_(pa) + xv.z * bl_(pb) + xv.w * bh_(pb);
            }
            { unsigned pc = wpk[64]; acc += h1s[t * 132 + 128] * bl_(pc) + h1s[t * 132 + 129] * bh_(pc); }
            xp[t * 520 + tid] = acc;
        }
        if (tid < 256) {
            int je = tid & 7, t = tid >> 3;
            float a = bih1[512 + je] + bhh1[512 + je];
            for (int k = 0; k < 130; k++) a += h1s[t * 132 + k] * WeX[k * 8 + je];
            xp[t * 520 + 512 + je] = a;
        }
    }
    __syncthreads();

    #pragma unroll
    for (int kk = 0; kk < 65; kk++) wpk[kk] = wp_hh1[kk * 520 + tid];
    for (int l = tid; l < 130 * 8; l += 512) { int k = l >> 3, je = l & 7; WeX[l] = Whh1[(512 + je) * 130 + k]; }
    for (int l = tid; l < 132; l += 512) { hS[l] = 0.f; cS[l] = 0.f; }
    __syncthreads();
    {
        float we0 = WeX[lane * 8 + wv];
        float we1 = WeX[(lane + 64) * 8 + wv];
        float we2 = (lane < 2) ? WeX[(lane + 128) * 8 + wv] : 0.f;
        for (int t = 0; t < 32; t++) {
            float acc = xp[t * 520 + tid];
            const float4* h4 = (const float4*)hS;
            #pragma unroll
            for (int q = 0; q < 32; q++) {
                float4 hv = h4[q];
                unsigned pa = wpk[2 * q], pb = wpk[2 * q + 1];
                acc += hv.x * bl_(pa) + hv.y * bh_(pa) + hv.z * bl_(pb) + hv.w * bh_(pb);
            }
            { unsigned pc = wpk[64]; acc += hS[128] * bl_(pc) + hS[129] * bh_(pc); }
            gS[tid] = acc;
            float p = hS[lane] * we0 + hS[lane + 64] * we1;
            if (lane < 2) p += hS[lane + 128] * we2;
            #pragma unroll
            for (int off = 32; off >= 1; off >>= 1) p += __shfl_xor(p, off);
            if (lane == 0) gS[512 + wv] = xp[t * 520 + 512 + wv] + p;
            __syncthreads();
            if (tid < 130) {
                float iv = sigmoidf_(gS[tid]);
                float fv = sigmoidf_(gS[130 + tid]);
                float gv = tanhf_(gS[260 + tid]);
                float ov = sigmoidf_(gS[390 + tid]);
                float cv = fv * cS[tid] + iv * gv;
                cS[tid] = cv;
                float hv = ov * tanhf_(cv);
                hS[tid] = hv;
                if (t == 31) h2last[(size_t)b * LH + tid] = hv;
            }
            __syncthreads();
        }
    }
}

// ------------- final -------------
__global__ __launch_bounds__(256) void final_kernel(const float* __restrict__ state,
                                                    const float* __restrict__ h2last,
                                                    const float* __restrict__ fcW,
                                                    const float* __restrict__ fcb,
                                                    float* __restrict__ out) {
    const int b = blockIdx.x;
    const int tid = threadIdx.x;
    __shared__ float feat[LH + HH];
    __shared__ float red[4][HH];
    const int hh = tid & 63, q = tid >> 6;
    float mx = -INFINITY;
    for (int n = q * 128; n < q * 128 + 128; n++)
        mx = fmaxf(mx, state[((size_t)b * NN + n) * HH + hh]);
    red[q][hh] = mx;
    if (tid >= 64 && tid < 64 + LH)
        feat[tid - 64] = h2last[(size_t)b * LH + (tid - 64)];
    __syncthreads();
    if (tid < HH)
        feat[LH + tid] = fmaxf(fmaxf(red[0][tid], red[1][tid]), fmaxf(red[2][tid], red[3][tid]));
    __syncthreads();
    if (tid < 24) {
        float a = fcb[tid];
        for (int k = 0; k < LH + HH; k++) a += feat[k] * fcW[tid * (LH + HH) + k];
        out[b * 24 + tid] = sigmoidf_(a);
    }
}

extern "C" void kernel_launch(void* const* d_in, const int* in_sizes, int n_in,
                              void* d_out, int out_size, void* d_ws, size_t ws_size,
                              hipStream_t stream) {
    const float* ent  = (const float*)d_in[0];
    const float* mask = (const float*)d_in[1];
    const float* sr   = (const float*)d_in[2];
    const float* emb  = (const float*)d_in[3];
    const float* gW   = (const float*)d_in[4];
    const float* gb   = (const float*)d_in[5];
    const float* uW   = (const float*)d_in[6];
    const float* ub   = (const float*)d_in[7];
    const float* Wih0 = (const float*)d_in[8];
    const float* Whh0 = (const float*)d_in[9];
    const float* bih0 = (const float*)d_in[10];
    const float* bhh0 = (const float*)d_in[11];
    const float* Wih1 = (const float*)d_in[12];
    const float* Whh1 = (const float*)d_in[13];
    const float* bih1 = (const float*)d_in[14];
    const float* bhh1 = (const float*)d_in[15];
    const float* fcW  = (const float*)d_in[16];
    const float* fcb  = (const float*)d_in[17];
    float* out = (float*)d_out;
    float* ws = (float*)d_ws;

    size_t off = 0;
    float* Sb     = ws + off; off += (size_t)NN * NN;
    unsigned short* WgF = (unsigned short*)(ws + off); off += (size_t)NN * 8 * 5 * 512;
    unsigned short* WuF = (unsigned short*)(ws + off); off += (size_t)NN * 4 * 5 * 512;
    float* bgc    = ws + off; off += (size_t)NN * 128;
    float* buc    = ws + off; off += (size_t)NN * HH;
    float* state  = ws + off; off += (size_t)BB * NN * HH;
    float* xgP    = ws + off; off += 2 * PART;
    float* cand   = ws + off; off += PART;
    float* rbuf   = ws + off; off += (size_t)BB * NN * HH;
    float* h2last = ws + off; off += (size_t)BB * LH;
    unsigned* wp_ih0 = (unsigned*)(ws + off); off += 32 * LG;
    unsigned* wp_hh0 = (unsigned*)(ws + off); off += 65 * LG;
    unsigned* wp_ih1 = (unsigned*)(ws + off); off += 65 * LG;
    unsigned* wp_hh1 = (unsigned*)(ws + off); off += 65 * LG;

    // ---- one-time precompute ----
    sbase_kernel<<<NN, 256, 0, stream>>>(emb, Sb);
    combine_frag_kernel<<<20480, 256, 0, stream>>>(emb, gW, WgF, 128, 8);
    combine_frag_kernel<<<20480, 256, 0, stream>>>(emb, uW, WuF, 64, 4);
    combine_kernel<<<256, 256, 0, stream>>>(emb, gb, bgc, 128, NN * 128);
    combine_kernel<<<128, 256, 0, stream>>>(emb, ub, buc, HH, NN * HH);
    pack_kernel<<<(32 * LG + 255) / 256, 256, 0, stream>>>(Wih0, wp_ih0, 64);
    pack_kernel<<<(65 * LG + 255) / 256, 256, 0, stream>>>(Whh0, wp_hh0, 130);
    pack_kernel<<<(65 * LG + 255) / 256, 256, 0, stream>>>(Wih1, wp_ih1, 130);
    pack_kernel<<<(65 * LG + 255) / 256, 256, 0, stream>>>(Whh1, wp_hh1, 130);

    // ---- persistent cooperative GRU (12 timesteps, 49 grid syncs) ----
    {
        void* cargs[] = {(void*)&Sb, (void*)&mask, (void*)&ent, (void*)&state,
                         (void*)&cand, (void*)&xgP, (void*)&WgF, (void*)&bgc,
                         (void*)&WuF, (void*)&buc, (void*)&rbuf};
        hipLaunchCooperativeKernel((void*)gru_coop_kernel, dim3(256), dim3(256),
                                   cargs, 0, stream);
    }

    // ---- fused LSTM stack ----
    lstm_fused_kernel<<<BB, 512, 0, stream>>>(sr, wp_ih0, Wih0, bih0, bhh0, wp_hh0, Whh0,
                                              wp_ih1, Wih1, bih1, bhh1, wp_hh1, Whh1, h2last);

    // ---- final ----
    final_kernel<<<BB, 256, 0, stream>>>(state, h2last, fcW, fcb, out);
}

// Round 6
// 1101.106 us; speedup vs baseline: 2.8525x; 2.8525x over previous
//
#include <hip/hip_runtime.h>
#include <math.h>

#define NN 512
#define EMBD 10
#define HH 64
#define DINV 2
#define CIN 66
#define TT 12
#define BB 16
#define LH 130
#define LG 520
#define PART ((size_t)BB * NN * CIN)

typedef __attribute__((ext_vector_type(8))) short short8;
typedef __attribute__((ext_vector_type(4))) float f32x4;

__device__ __forceinline__ float sigmoidf_(float x) { return 1.f / (1.f + __expf(-x)); }
__device__ __forceinline__ float tanhf_(float x)    { return 1.f - 2.f / (1.f + __expf(2.f * x)); }
__device__ __forceinline__ float bl_(unsigned p) { return __uint_as_float(p << 16); }
__device__ __forceinline__ float bh_(unsigned p) { return __uint_as_float(p & 0xffff0000u); }
__device__ __forceinline__ unsigned bf16rne_(float f) {
    unsigned u = __float_as_uint(f);
    u += 0x7fff + ((u >> 16) & 1);
    return u >> 16;
}
__device__ __forceinline__ void split_(float v, unsigned& hi, unsigned& lo) {
    hi = bf16rne_(v);
    float hif = __uint_as_float(hi << 16);
    lo = bf16rne_(v - hif);
}

// ---------------- S_base = softmax(relu(emb @ emb^T)) ----------------
__global__ __launch_bounds__(256) void sbase_kernel(const float* __restrict__ emb,
                                                    float* __restrict__ Sb) {
    const int n = blockIdx.x;
    const int tid = threadIdx.x;
    __shared__ float en[EMBD];
    __shared__ float redw[4];
    if (tid < EMBD) en[tid] = emb[n * EMBD + tid];
    __syncthreads();
    float v[2];
    #pragma unroll
    for (int q = 0; q < 2; q++) {
        int m = tid + q * 256;
        float s = 0.f;
        #pragma unroll
        for (int d = 0; d < EMBD; d++) s += en[d] * emb[m * EMBD + d];
        v[q] = fmaxf(s, 0.f);
    }
    float mx = fmaxf(v[0], v[1]);
    for (int off = 32; off >= 1; off >>= 1) mx = fmaxf(mx, __shfl_xor(mx, off));
    if ((tid & 63) == 0) redw[tid >> 6] = mx;
    __syncthreads();
    mx = fmaxf(fmaxf(redw[0], redw[1]), fmaxf(redw[2], redw[3]));
    __syncthreads();
    v[0] = __expf(v[0] - mx);
    v[1] = __expf(v[1] - mx);
    float sm = v[0] + v[1];
    for (int off = 32; off >= 1; off >>= 1) sm += __shfl_xor(sm, off);
    if ((tid & 63) == 0) redw[tid >> 6] = sm;
    __syncthreads();
    sm = redw[0] + redw[1] + redw[2] + redw[3];
    float inv = 1.f / sm;
    Sb[n * NN + tid]       = v[0] * inv;
    Sb[n * NN + tid + 256] = v[1] * inv;
}

// ------------- per-node biases (f32) -------------
__global__ __launch_bounds__(256) void combine_kernel(const float* __restrict__ emb,
                                                      const float* __restrict__ pool,
                                                      float* __restrict__ out,
                                                      int per_n, int total) {
    for (int idx = blockIdx.x * 256 + threadIdx.x; idx < total; idx += gridDim.x * 256) {
        int n = idx / per_n;
        int rem = idx - n * per_n;
        float a = 0.f;
        #pragma unroll
        for (int d = 0; d < EMBD; d++) a += emb[n * EMBD + d] * pool[d * per_n + rem];
        out[idx] = a;
    }
}

// ------------- per-node weights -> fragment-ordered bf16 hi/lo -------------
__global__ __launch_bounds__(256) void combine_frag_kernel(const float* __restrict__ emb,
                                                           const float* __restrict__ pool,
                                                           unsigned short* __restrict__ outU,
                                                           int O, int OT) {
    size_t total = (size_t)NN * OT * 5 * 512;
    for (size_t idx = (size_t)blockIdx.x * 256 + threadIdx.x; idx < total;
         idx += (size_t)gridDim.x * 256) {
        int j = idx & 7;
        int l = (idx >> 3) & 63;
        size_t r = idx >> 9;
        int kc = (int)(r % 5); r /= 5;
        int ot = (int)(r % OT);
        int n  = (int)(r / OT);
        int kp = kc * 32 + ((l >> 4) << 3) + j;
        int o = ot * 16 + (l & 15);
        float v = 0.f;
        if (kp < 2 * CIN) {
            int kk = (kp >= CIN) ? 1 : 0;
            int i = kp - CIN * kk;
            const float* p = pool + ((size_t)(kk * CIN + i)) * O + o;
            #pragma unroll
            for (int d = 0; d < EMBD; d++)
                v += emb[n * EMBD + d] * p[(size_t)d * (2 * CIN) * O];
        }
        unsigned hi, lo;
        split_(v, hi, lo);
        size_t base = (((size_t)n * OT + ot) * 5 + kc) * 1024;
        outU[base + l * 8 + j] = (unsigned short)hi;
        outU[base + 512 + l * 8 + j] = (unsigned short)lo;
    }
}

// ------------- pack LSTM weights -------------
__global__ __launch_bounds__(256) void pack_kernel(const float* __restrict__ w,
                                                   unsigned* __restrict__ wp, int K) {
    int idx = blockIdx.x * 256 + threadIdx.x;
    int KH = K >> 1;
    if (idx < KH * LG) {
        int kk = idx / LG, j = idx - kk * LG;
        wp[idx] = bf16rne_(w[j * K + 2 * kk]) | (bf16rne_(w[j * K + 2 * kk + 1]) << 16);
    }
}

__global__ __launch_bounds__(256) void zero_kernel(float* __restrict__ p, int n) {
    int i = blockIdx.x * 256 + threadIdx.x;
    if (i < n) p[i] = 0.f;
}

// ------------- build frag-ordered bf16 hi/lo of X (B operand for spmm) -------------
// frag(b,q,ct,kc): base = ((((b*8+q)*5+ct)*2+kc)*1024 ushorts; [0..512) hi, [512..1024) lo
// element (lane l, j): X[m = q*64 + kc*32 + ((l>>4)&3)*8 + j][c = ct*16 + (l&15)]
// mode 0: X = concat(ent[:,t], state); mode 1: X = cand.  81920 threads = 320 blocks.
__global__ __launch_bounds__(256) void xfrag_kernel(const float* __restrict__ ent,
                                                    const float* __restrict__ state,
                                                    const float* __restrict__ cand,
                                                    unsigned short* __restrict__ Xf,
                                                    int t, int mode) {
    int idx = blockIdx.x * 256 + threadIdx.x;
    int l = idx & 63;
    int r = idx >> 6;
    int kc = r & 1; r >>= 1;
    int ct = r % 5; r /= 5;
    int q = r & 7;
    int b = r >> 3;
    const int c = ct * 16 + (l & 15);
    const int mbase = q * 64 + kc * 32 + ((l >> 4) & 3) * 8;
    union { unsigned short u[8]; short8 v; } hi8, lo8;
    #pragma unroll
    for (int j = 0; j < 8; j++) {
        int m = mbase + j;
        float v = 0.f;
        if (c < CIN) {
            if (mode == 0) {
                v = (c < DINV) ? ent[((size_t)(b * TT + t) * NN + m) * DINV + c]
                               : state[((size_t)b * NN + m) * HH + (c - DINV)];
            } else {
                v = cand[(size_t)b * NN * CIN + m * CIN + c];
            }
        }
        unsigned hi, lo;
        split_(v, hi, lo);
        hi8.u[j] = (unsigned short)hi;
        lo8.u[j] = (unsigned short)lo;
    }
    size_t base = ((((size_t)b * 8 + q) * 5 + ct) * 2 + kc) * 1024;
    *(short8*)(Xf + base + l * 8) = hi8.v;
    *(short8*)(Xf + base + 512 + l * 8) = lo8.v;
}

// ------------- spmm: no LDS, no barriers. grid (8 ntiles, 16 b, 4 K-quarters) -------------
__global__ __launch_bounds__(256) void spmm_kernel(const float* __restrict__ Sb,
                                                   const float* __restrict__ mask,
                                                   const unsigned short* __restrict__ Xf,
                                                   float* __restrict__ out, int t) {
    const int tid = threadIdx.x;
    const int lane = tid & 63;
    const int w = tid >> 6;
    const int n0 = blockIdx.x * 64;
    const int b = blockIdx.y;
    const int z = blockIdx.z;
    float* __restrict__ outp = out + (size_t)z * PART;
    const float* __restrict__ mrow = mask + (size_t)(b * TT + t) * NN * NN;
    const int nrow = n0 + w * 16 + (lane & 15);
    const int mgrp = ((lane >> 4) & 3) * 8;

    f32x4 acc[5];
    #pragma unroll
    for (int ct = 0; ct < 5; ct++) acc[ct] = (f32x4){0.f, 0.f, 0.f, 0.f};

    #pragma unroll
    for (int r2 = 0; r2 < 2; r2++) {
        const int q = z * 2 + r2;
        #pragma unroll
        for (int kc = 0; kc < 2; kc++) {
            const int mstart = q * 64 + kc * 32 + mgrp;
            const float4* s4 = (const float4*)(Sb + (size_t)nrow * NN + mstart);
            const float4* m4 = (const float4*)(mrow + (size_t)nrow * NN + mstart);
            float4 sa = s4[0], sc = s4[1];
            float4 ma = m4[0], mc = m4[1];
            float pv[8] = {sa.x * ma.x, sa.y * ma.y, sa.z * ma.z, sa.w * ma.w,
                           sc.x * mc.x, sc.y * mc.y, sc.z * mc.z, sc.w * mc.w};
            union { unsigned short u[8]; short8 v; } ah, al;
            #pragma unroll
            for (int j = 0; j < 8; j++) {
                unsigned hi, lo;
                split_(pv[j], hi, lo);
                ah.u[j] = (unsigned short)hi;
                al.u[j] = (unsigned short)lo;
            }
            #pragma unroll
            for (int ct = 0; ct < 5; ct++) {
                size_t base = ((((size_t)b * 8 + q) * 5 + ct) * 2 + kc) << 10;
                short8 bh = *(const short8*)(Xf + base + lane * 8);
                short8 bl = *(const short8*)(Xf + base + 512 + lane * 8);
                acc[ct] = __builtin_amdgcn_mfma_f32_16x16x32_bf16(ah.v, bh, acc[ct], 0, 0, 0);
                acc[ct] = __builtin_amdgcn_mfma_f32_16x16x32_bf16(ah.v, bl, acc[ct], 0, 0, 0);
                acc[ct] = __builtin_amdgcn_mfma_f32_16x16x32_bf16(al.v, bh, acc[ct], 0, 0, 0);
            }
        }
    }
    const int col = lane & 15, rq = lane >> 4;
    #pragma unroll
    for (int ct = 0; ct < 5; ct++) {
        int c = ct * 16 + col;
        if (c < CIN) {
            #pragma unroll
            for (int reg = 0; reg < 4; reg++) {
                int n = n0 + w * 16 + rq * 4 + reg;
                outp[(size_t)b * NN * CIN + n * CIN + c] = acc[ct][reg];
            }
        }
    }
}

// ------------- gate via MFMA: per-n GEMM M=16(b) N=128(o) K=132(pad160) -------------
__global__ __launch_bounds__(256) void gate_mfma_kernel(const float* __restrict__ ent,
                                                        const float* __restrict__ state,
                                                        const float* __restrict__ xg1,
                                                        const unsigned short* __restrict__ WgF,
                                                        const float* __restrict__ bg,
                                                        float* __restrict__ cand,
                                                        float* __restrict__ rbuf,
                                                        int t) {
    __shared__ unsigned short A_h[16 * 168], A_l[16 * 168];
    const int n = blockIdx.x;
    const int tid = threadIdx.x;
    const int lane = tid & 63;
    const int w = tid >> 6;
    for (int idx = tid; idx < 16 * 36; idx += 256) {
        int b = idx / 36, k = 132 + idx - b * 36;
        A_h[b * 168 + k] = 0; A_l[b * 168 + k] = 0;
    }
    for (int idx = tid; idx < 16 * 132; idx += 256) {
        int b = idx / 132, ip = idx - b * 132;
        float v;
        if (ip < CIN) {
            v = (ip < DINV) ? ent[((size_t)(b * TT + t) * NN + n) * DINV + ip]
                            : state[((size_t)b * NN + n) * HH + (ip - DINV)];
        } else {
            size_t g = (size_t)b * NN * CIN + n * CIN + (ip - CIN);
            v = xg1[g] + xg1[g + PART] + xg1[g + 2 * PART] + xg1[g + 3 * PART];
        }
        unsigned hi, lo;
        split_(v, hi, lo);
        A_h[b * 168 + ip] = (unsigned short)hi;
        A_l[b * 168 + ip] = (unsigned short)lo;
    }
    __syncthreads();

    f32x4 acc0 = {0.f, 0.f, 0.f, 0.f}, acc1 = {0.f, 0.f, 0.f, 0.f};
    const unsigned short* Wn = WgF + (size_t)n * (8 * 5 * 1024);
    #pragma unroll
    for (int kc = 0; kc < 5; kc++) {
        int aoff = (lane & 15) * 168 + kc * 32 + (lane >> 4) * 8;
        short8 ah = *(const short8*)&A_h[aoff];
        short8 al = *(const short8*)&A_l[aoff];
        const unsigned short* f0 = Wn + ((size_t)(w * 5) + kc) * 1024 + lane * 8;
        short8 bh = *(const short8*)f0;
        short8 bl = *(const short8*)(f0 + 512);
        acc0 = __builtin_amdgcn_mfma_f32_16x16x32_bf16(ah, bh, acc0, 0, 0, 0);
        acc0 = __builtin_amdgcn_mfma_f32_16x16x32_bf16(ah, bl, acc0, 0, 0, 0);
        acc0 = __builtin_amdgcn_mfma_f32_16x16x32_bf16(al, bh, acc0, 0, 0, 0);
        const unsigned short* f1 = Wn + ((size_t)((w + 4) * 5) + kc) * 1024 + lane * 8;
        short8 bh1 = *(const short8*)f1;
        short8 bl1 = *(const short8*)(f1 + 512);
        acc1 = __builtin_amdgcn_mfma_f32_16x16x32_bf16(ah, bh1, acc1, 0, 0, 0);
        acc1 = __builtin_amdgcn_mfma_f32_16x16x32_bf16(ah, bl1, acc1, 0, 0, 0);
        acc1 = __builtin_amdgcn_mfma_f32_16x16x32_bf16(al, bh1, acc1, 0, 0, 0);
    }
    const int col = lane & 15, rq = lane >> 4;
    #pragma unroll
    for (int e = 0; e < 2; e++) {
        int o = (w + e * 4) * 16 + col;
        f32x4 a = e ? acc1 : acc0;
        float bias = bg[n * 128 + o];
        #pragma unroll
        for (int reg = 0; reg < 4; reg++) {
            int b = rq * 4 + reg;
            float zr = sigmoidf_(a[reg] + bias);
            if (o < HH)
                cand[(size_t)b * NN * CIN + n * CIN + DINV + o] =
                    zr * state[((size_t)b * NN + n) * HH + o];
            else
                rbuf[((size_t)b * NN + n) * HH + (o - HH)] = zr;
        }
    }
    if (tid < 32) {
        int b = tid >> 1, i = tid & 1;
        cand[(size_t)b * NN * CIN + n * CIN + i] =
            ent[((size_t)(b * TT + t) * NN + n) * DINV + i];
    }
}

// ------------- update via MFMA: per-n GEMM M=16 N=64 K=132(pad160) -------------
__global__ __launch_bounds__(256) void update_mfma_kernel(const float* __restrict__ cand,
                                                          const float* __restrict__ xg2,
                                                          const unsigned short* __restrict__ WuF,
                                                          const float* __restrict__ bu,
                                                          const float* __restrict__ rbuf,
                                                          float* __restrict__ state) {
    __shared__ unsigned short A_h[16 * 168], A_l[16 * 168];
    const int n = blockIdx.x;
    const int tid = threadIdx.x;
    const int lane = tid & 63;
    const int w = tid >> 6;
    for (int idx = tid; idx < 16 * 36; idx += 256) {
        int b = idx / 36, k = 132 + idx - b * 36;
        A_h[b * 168 + k] = 0; A_l[b * 168 + k] = 0;
    }
    for (int idx = tid; idx < 16 * 132; idx += 256) {
        int b = idx / 132, ip = idx - b * 132;
        float v;
        if (ip < CIN) {
            v = cand[(size_t)b * NN * CIN + n * CIN + ip];
        } else {
            size_t g = (size_t)b * NN * CIN + n * CIN + (ip - CIN);
            v = xg2[g] + xg2[g + PART] + xg2[g + 2 * PART] + xg2[g + 3 * PART];
        }
        unsigned hi, lo;
        split_(v, hi, lo);
        A_h[b * 168 + ip] = (unsigned short)hi;
        A_l[b * 168 + ip] = (unsigned short)lo;
    }
    __syncthreads();

    f32x4 acc = {0.f, 0.f, 0.f, 0.f};
    const unsigned short* Wn = WuF + (size_t)n * (4 * 5 * 1024);
    #pragma unroll
    for (int kc = 0; kc < 5; kc++) {
        int aoff = (lane & 15) * 168 + kc * 32 + (lane >> 4) * 8;
        short8 ah = *(const short8*)&A_h[aoff];
        short8 al = *(const short8*)&A_l[aoff];
        const unsigned short* f0 = Wn + ((size_t)(w * 5) + kc) * 1024 + lane * 8;
        short8 bh = *(const short8*)f0;
        short8 bl = *(const short8*)(f0 + 512);
        acc = __builtin_amdgcn_mfma_f32_16x16x32_bf16(ah, bh, acc, 0, 0, 0);
        acc = __builtin_amdgcn_mfma_f32_16x16x32_bf16(ah, bl, acc, 0, 0, 0);
        acc = __builtin_amdgcn_mfma_f32_16x16x32_bf16(al, bh, acc, 0, 0, 0);
    }
    const int col = lane & 15, rq = lane >> 4;
    int o = w * 16 + col;
    float bias = bu[n * HH + o];
    #pragma unroll
    for (int reg = 0; reg < 4; reg++) {
        int b = rq * 4 + reg;
        float hc = tanhf_(acc[reg] + bias);
        size_t g = ((size_t)b * NN + n) * HH + o;
        float rr = rbuf[g];
        state[g] = rr * state[g] + (1.f - rr) * hc;
    }
}

// ------------- fused 2-layer LSTM (unchanged) -------------
__global__ __launch_bounds__(512) void lstm_fused_kernel(
    const float* __restrict__ sr,
    const unsigned* __restrict__ wp_ih0, const float* __restrict__ Wih0,
    const float* __restrict__ bih0, const float* __restrict__ bhh0,
    const unsigned* __restrict__ wp_hh0, const float* __restrict__ Whh0,
    const unsigned* __restrict__ wp_ih1, const float* __restrict__ Wih1,
    const float* __restrict__ bih1, const float* __restrict__ bhh1,
    const unsigned* __restrict__ wp_hh1, const float* __restrict__ Whh1,
    float* __restrict__ h2last) {
    const int b = blockIdx.x;
    const int tid = threadIdx.x;
    const int lane = tid & 63;
    const int wv = tid >> 6;
    __shared__ __align__(16) float xp[32 * 520];
    __shared__ __align__(16) float h1s[32 * 132];
    __shared__ __align__(16) float xs[32 * 64];
    __shared__ __align__(16) float hS[132], cS[132];
    __shared__ float gS[520];
    __shared__ float WeX[130 * 8];
    unsigned wpk[65];

    for (int l = tid; l < 32 * 64; l += 512) xs[l] = sr[(size_t)b * 2048 + l];
    #pragma unroll
    for (int kk = 0; kk < 32; kk++) wpk[kk] = wp_ih0[kk * 520 + tid];
    for (int l = tid; l < 64 * 8; l += 512) { int k = l >> 3, je = l & 7; WeX[l] = Wih0[(512 + je) * 64 + k]; }
    __syncthreads();
    {
        float bias = bih0[tid] + bhh0[tid];
        for (int t = 0; t < 32; t++) {
            const float4* x4 = (const float4*)&xs[t * 64];
            float acc = bias;
            #pragma unroll
            for (int q = 0; q < 16; q++) {
                float4 xv = x4[q];
                unsigned pa = wpk[2 * q], pb = wpk[2 * q + 1];
                acc += xv.x * bl_(pa) + xv.y * bh_(pa) + xv.z * bl_(pb) + xv.w * bh_(pb);
            }
            xp[t * 520 + tid] = acc;
        }
        if (tid < 256) {
            int je = tid & 7, t = tid >> 3;
            float a = bih0[512 + je] + bhh0[512 + je];
            for (int k = 0; k < 64; k++) a += xs[t * 64 + k] * WeX[k * 8 + je];
            xp[t * 520 + 512 + je] = a;
        }
    }
    __syncthreads();

    #pragma unroll
    for (int kk = 0; kk < 65; kk++) wpk[kk] = wp_hh0[kk * 520 + tid];
    for (int l = tid; l < 130 * 8; l += 512) { int k = l >> 3, je = l & 7; WeX[l] = Whh0[(512 + je) * 130 + k]; }
    for (int l = tid; l < 132; l += 512) { hS[l] = 0.f; cS[l] = 0.f; }
    __syncthreads();
    {
        float we0 = WeX[lane * 8 + wv];
        float we1 = WeX[(lane + 64) * 8 + wv];
        float we2 = (lane < 2) ? WeX[(lane + 128) * 8 + wv] : 0.f;
        for (int t = 0; t < 32; t++) {
            float acc = xp[t * 520 + tid];
            const float4* h4 = (const float4*)hS;
            #pragma unroll
            for (int q = 0; q < 32; q++) {
                float4 hv = h4[q];
                unsigned pa = wpk[2 * q], pb = wpk[2 * q + 1];
                acc += hv.x * bl_(pa) + hv.y * bh_(pa) + hv.z * bl_(pb) + hv.w * bh_(pb);
            }
            { unsigned pc = wpk[64]; acc += hS[128] * bl_(pc) + hS[129] * bh_(pc); }
            gS[tid] = acc;
            float p = hS[lane] * we0 + hS[lane + 64] * we1;
            if (lane < 2) p += hS[lane + 128] * we2;
            #pragma unroll
            for (int off = 32; off >= 1; off >>= 1) p += __shfl_xor(p, off);
            if (lane == 0) gS[512 + wv] = xp[t * 520 + 512 + wv] + p;
            __syncthreads();
            if (tid < 130) {
                float iv = sigmoidf_(gS[tid]);
                float fv = sigmoidf_(gS[130 + tid]);
                float gv = tanhf_(gS[260 + tid]);
                float ov = sigmoidf_(gS[390 + tid]);
                float cv = fv * cS[tid] + iv * gv;
                cS[tid] = cv;
                float hv = ov * tanhf_(cv);
                hS[tid] = hv;
                h1s[t * 132 + tid] = hv;
            }
            __syncthreads();
        }
    }

    #pragma unroll
    for (int kk = 0; kk < 65; kk++) wpk[kk] = wp_ih1[kk * 520 + tid];
    for (int l = tid; l < 130 * 8; l += 512) { int k = l >> 3, je = l & 7; WeX[l] = Wih1[(512 + je) * 130 + k]; }
    __syncthreads();
    {
        float bias = bih1[tid] + bhh1[tid];
        for (int t = 0; t < 32; t++) {
            const float4* x4 = (const float4*)&h1s[t * 132];
            float acc = bias;
            #pragma unroll
            for (int q = 0; q < 32; q++) {
                float4 xv = x4[q];
                unsigned pa = wpk[2 * q], pb = wpk[2 * q + 1];
                acc += xv.x * bl_(pa) + xv.y * bh_(pa) + xv.z * bl_(pb) + xv.w * bh_(pb);
            }
            { unsigned pc = wpk[64]; acc += h1s[t * 132 + 128] * bl_(pc) + h1s[t * 132 + 129] * bh_(pc); }
            xp[t * 520 + tid] = acc;
        }
        if (tid < 256) {
            int je = tid & 7, t = tid >> 3;
            float a = bih1[512 + je] + bhh1[512 + je];
            for (int k = 0; k < 130; k++) a += h1s[t * 132 + k] * WeX[k * 8 + je];
            xp[t * 520 + 512 + je] = a;
        }
    }
    __syncthreads();

    #pragma unroll
    for (int kk = 0; kk < 65; kk++) wpk[kk] = wp_hh1[kk * 520 + tid];
    for (int l = tid; l < 130 * 8; l += 512) { int k = l >> 3, je = l & 7; WeX[l] = Whh1[(512 + je) * 130 + k]; }
    for (int l = tid; l < 132; l += 512) { hS[l] = 0.f; cS[l] = 0.f; }
    __syncthreads();
    {
        float we0 = WeX[lane * 8 + wv];
        float we1 = WeX[(lane + 64) * 8 + wv];
        float we2 = (lane < 2) ? WeX[(lane + 128) * 8 + wv] : 0.f;
        for (int t = 0; t < 32; t++) {
            float acc = xp[t * 520 + tid];
            const float4* h4 = (const float4*)hS;
            #pragma unroll
            for (int q = 0; q < 32; q++) {
                float4 hv = h4[q];
                unsigned pa = wpk[2 * q], pb = wpk[2 * q + 1];
                acc += hv.x * bl_(pa) + hv.y * bh_(pa) + hv.z * bl_(pb) + hv.w * bh_(pb);
            }
            { unsigned pc = wpk[64]; acc += hS[128] * bl_(pc) + hS[129] * bh_(pc); }
            gS[tid] = acc;
            float p = hS[lane] * we0 + hS[lane + 64] * we1;
            if (lane < 2) p += hS[lane + 128] * we2;
            #pragma unroll
            for (int off = 32; off >= 1; off >>= 1) p += __shfl_xor(p, off);
            if (lane == 0) gS[512 + wv] = xp[t * 520 + 512 + wv] + p;
            __syncthreads();
            if (tid < 130) {
                float iv = sigmoidf_(gS[tid]);
                float fv = sigmoidf_(gS[130 + tid]);
                float gv = tanhf_(gS[260 + tid]);
                float ov = sigmoidf_(gS[390 + tid]);
                float cv = fv * cS[tid] + iv * gv;
                cS[tid] = cv;
                float hv = ov * tanhf_(cv);
                hS[tid] = hv;
                if (t == 31) h2last[(size_t)b * LH + tid] = hv;
            }
            __syncthreads();
        }
    }
}

// ------------- final -------------
__global__ __launch_bounds__(256) void final_kernel(const float* __restrict__ state,
                                                    const float* __restrict__ h2last,
                                                    const float* __restrict__ fcW,
                                                    const float* __restrict__ fcb,
                                                    float* __restrict__ out) {
    const int b = blockIdx.x;
    const int tid = threadIdx.x;
    __shared__ float feat[LH + HH];
    __shared__ float red[4][HH];
    const int hh = tid & 63, q = tid >> 6;
    float mx = -INFINITY;
    for (int n = q * 128; n < q * 128 + 128; n++)
        mx = fmaxf(mx, state[((size_t)b * NN + n) * HH + hh]);
    red[q][hh] = mx;
    if (tid >= 64 && tid < 64 + LH)
        feat[tid - 64] = h2last[(size_t)b * LH + (tid - 64)];
    __syncthreads();
    if (tid < HH)
        feat[LH + tid] = fmaxf(fmaxf(red[0][tid], red[1][tid]), fmaxf(red[2][tid], red[3][tid]));
    __syncthreads();
    if (tid < 24) {
        float a = fcb[tid];
        for (int k = 0; k < LH + HH; k++) a += feat[k] * fcW[tid * (LH + HH) + k];
        out[b * 24 + tid] = sigmoidf_(a);
    }
}

extern "C" void kernel_launch(void* const* d_in, const int* in_sizes, int n_in,
                              void* d_out, int out_size, void* d_ws, size_t ws_size,
                              hipStream_t stream) {
    const float* ent  = (const float*)d_in[0];
    const float* mask = (const float*)d_in[1];
    const float* sr   = (const float*)d_in[2];
    const float* emb  = (const float*)d_in[3];
    const float* gW   = (const float*)d_in[4];
    const float* gb   = (const float*)d_in[5];
    const float* uW   = (const float*)d_in[6];
    const float* ub   = (const float*)d_in[7];
    const float* Wih0 = (const float*)d_in[8];
    const float* Whh0 = (const float*)d_in[9];
    const float* bih0 = (const float*)d_in[10];
    const float* bhh0 = (const float*)d_in[11];
    const float* Wih1 = (const float*)d_in[12];
    const float* Whh1 = (const float*)d_in[13];
    const float* bih1 = (const float*)d_in[14];
    const float* bhh1 = (const float*)d_in[15];
    const float* fcW  = (const float*)d_in[16];
    const float* fcb  = (const float*)d_in[17];
    float* out = (float*)d_out;
    float* ws = (float*)d_ws;

    size_t off = 0;
    float* Sb     = ws + off; off += (size_t)NN * NN;
    unsigned short* WgF = (unsigned short*)(ws + off); off += (size_t)NN * 8 * 5 * 512;
    unsigned short* WuF = (unsigned short*)(ws + off); off += (size_t)NN * 4 * 5 * 512;
    float* bgc    = ws + off; off += (size_t)NN * 128;
    float* buc    = ws + off; off += (size_t)NN * HH;
    float* state  = ws + off; off += (size_t)BB * NN * HH;
    float* xgP    = ws + off; off += 4 * PART;
    float* cand   = ws + off; off += PART;
    float* rbuf   = ws + off; off += (size_t)BB * NN * HH;
    float* h2last = ws + off; off += (size_t)BB * LH;
    unsigned short* Xf = (unsigned short*)(ws + off); off += (size_t)BB * 8 * 5 * 2 * 512;
    unsigned* wp_ih0 = (unsigned*)(ws + off); off += 32 * LG;
    unsigned* wp_hh0 = (unsigned*)(ws + off); off += 65 * LG;
    unsigned* wp_ih1 = (unsigned*)(ws + off); off += 65 * LG;
    unsigned* wp_hh1 = (unsigned*)(ws + off); off += 65 * LG;

    // ---- one-time precompute ----
    sbase_kernel<<<NN, 256, 0, stream>>>(emb, Sb);
    combine_frag_kernel<<<20480, 256, 0, stream>>>(emb, gW, WgF, 128, 8);
    combine_frag_kernel<<<20480, 256, 0, stream>>>(emb, uW, WuF, 64, 4);
    combine_kernel<<<256, 256, 0, stream>>>(emb, gb, bgc, 128, NN * 128);
    combine_kernel<<<128, 256, 0, stream>>>(emb, ub, buc, HH, NN * HH);
    pack_kernel<<<(32 * LG + 255) / 256, 256, 0, stream>>>(Wih0, wp_ih0, 64);
    pack_kernel<<<(65 * LG + 255) / 256, 256, 0, stream>>>(Whh0, wp_hh0, 130);
    pack_kernel<<<(65 * LG + 255) / 256, 256, 0, stream>>>(Wih1, wp_ih1, 130);
    pack_kernel<<<(65 * LG + 255) / 256, 256, 0, stream>>>(Whh1, wp_hh1, 130);
    zero_kernel<<<(BB * NN * HH + 255) / 256, 256, 0, stream>>>(state, BB * NN * HH);

    // ---- GRU over 12 timesteps ----
    for (int t = 0; t < TT; t++) {
        xfrag_kernel<<<320, 256, 0, stream>>>(ent, state, nullptr, Xf, t, 0);
        spmm_kernel<<<dim3(8, BB, 4), 256, 0, stream>>>(Sb, mask, Xf, xgP, t);
        gate_mfma_kernel<<<NN, 256, 0, stream>>>(ent, state, xgP, WgF, bgc, cand, rbuf, t);
        xfrag_kernel<<<320, 256, 0, stream>>>(nullptr, nullptr, cand, Xf, t, 1);
        spmm_kernel<<<dim3(8, BB, 4), 256, 0, stream>>>(Sb, mask, Xf, xgP, t);
        update_mfma_kernel<<<NN, 256, 0, stream>>>(cand, xgP, WuF, buc, rbuf, state);
    }

    // ---- fused LSTM stack ----
    lstm_fused_kernel<<<BB, 512, 0, stream>>>(sr, wp_ih0, Wih0, bih0, bhh0, wp_hh0, Whh0,
                                              wp_ih1, Wih1, bih1, bhh1, wp_hh1, Whh1, h2last);

    // ---- final ----
    final_kernel<<<BB, 256, 0, stream>>>(state, h2last, fcW, fcb, out);
}